// Round 10
// baseline (474.960 us; speedup 1.0000x reference)
//
#include <hip/hip_runtime.h>
#include <hip/hip_bf16.h>

typedef __attribute__((ext_vector_type(8))) short short8;   // 8 bf16 = 4 VGPRs (MFMA A/B frag)
typedef __attribute__((ext_vector_type(4))) float f32x4;    // MFMA C/D frag
typedef __attribute__((ext_vector_type(2))) float f32x2;    // packed-f32 (v_pk_*) pair

#define MFMA(a, b, c) __builtin_amdgcn_mfma_f32_16x16x32_bf16((a), (b), (c), 0, 0, 0)

__device__ __forceinline__ unsigned short f2bf(float f) {
    unsigned int u = __float_as_uint(f);
    u += 0x7fffu + ((u >> 16) & 1u);          // round-to-nearest-even
    return (unsigned short)(u >> 16);
}

// pack two f32 -> one u32 of 2x bf16 (RNE), single instruction
__device__ __forceinline__ unsigned int cvt_pk_bf16(float lo, float hi) {
    unsigned int d;
    asm("v_cvt_pk_bf16_f32 %0, %1, %2" : "=v"(d) : "v"(lo), "v"(hi));
    return d;
}

// 16-lane sum via DPP row_ror (VALU-only). Each 16-lane row gets its full sum.
template<int CTRL>
__device__ __forceinline__ float dpp_addf(float v) {
    int t = __builtin_amdgcn_update_dpp(0, __float_as_int(v), CTRL, 0xF, 0xF, true);
    return v + __int_as_float(t);
}
__device__ __forceinline__ float rowsum16(float v) {
    v = dpp_addf<0x121>(v);   // row_ror:1
    v = dpp_addf<0x122>(v);   // row_ror:2
    v = dpp_addf<0x124>(v);   // row_ror:4
    v = dpp_addf<0x128>(v);   // row_ror:8
    return v;
}

#if __has_builtin(__builtin_amdgcn_exp2f)
#define EXP2(x) __builtin_amdgcn_exp2f(x)
#else
#define EXP2(x) __expf((x) * 0.69314718f)
#endif

// gelu tanh-form: x*E/(E+1) = x - x/(E+1), E=exp2(x*(2.3021210+0.10295427 x^2)).
__device__ __forceinline__ float gelu_fast(float x) {
    float a = x * __builtin_fmaf(x * x, 0.10295427f, 2.3021210f);
    float E = EXP2(a);
    float r = __builtin_amdgcn_rcpf(E + 1.0f);
    return __builtin_fmaf(-x, r, x);          // x*E/(E+1)
}

// packed (2-wide) gelu for the edge stream
__device__ __forceinline__ f32x2 gelu_fast2(f32x2 x) {
    f32x2 c1 = {2.3021210f, 2.3021210f}, c2 = {0.10295427f, 0.10295427f};
    f32x2 a = x * __builtin_elementwise_fma(x * x, c2, c1);
    f32x2 E;
    E[0] = EXP2(a[0]); E[1] = EXP2(a[1]);
    f32x2 Ep = E + (f32x2){1.f, 1.f};
    f32x2 r;
    r[0] = __builtin_amdgcn_rcpf(Ep[0]); r[1] = __builtin_amdgcn_rcpf(Ep[1]);
    return __builtin_elementwise_fma(-x, r, x);
}

// unpack u32 of 2 bf16 -> f32x2 {lo, hi}
__device__ __forceinline__ f32x2 unpk_bf2(unsigned int a) {
    f32x2 r;
    r[0] = __uint_as_float(a << 16);
    r[1] = __uint_as_float(a & 0xffff0000u);
    return r;
}

// ---- weight fragment loaders --------------------------------------------
// scalar fallback: 8 strided f32 loads + converts
__device__ __forceinline__ short8 load_bfrag(const float* __restrict__ w, int k0, int n, int ldn) {
    short8 r;
#pragma unroll
    for (int u = 0; u < 8; ++u)
        r[u] = (short)f2bf(w[(k0 + u) * ldn + n]);
    return r;
}
// packed: ONE 16B load. WP[(n*(krows/8) + k0/8)*8 + u] = bf16(W[k0+u][n]).
__device__ __forceinline__ short8 load_bfrag_pk(const unsigned short* __restrict__ wp,
                                                int k0, int n, int krows) {
    return *(const short8*)&wp[(n * (krows >> 3) + (k0 >> 3)) << 3];
}

template<int R, int N1P>
struct SmemMlp {
    unsigned short sS[R * N1P];      // union: A [R][K+8] then gelu(h) [R][N1P]
    float rstat[R * 8];
};

// ---------------------------------------------------------------------------
// One MLP-head tile: out = gelu(LN(x@W1+b1)*g+be) @ W2 + b2 for MI*16 rows.
// 4 waves cooperative, fully unrolled. R5-proven tile sizes (FR MI=4, PH MI=2).
// ---------------------------------------------------------------------------
template<int K, int N1, int N2, int MI, bool PK>
__device__ void mlp_tile(SmemMlp<MI * 16, N1 + 8>& sm, const float* __restrict__ x,
                         const void* __restrict__ w1v, const float* __restrict__ b1,
                         const float* __restrict__ g, const float* __restrict__ be,
                         const void* __restrict__ w2v, const float* __restrict__ b2,
                         float* __restrict__ out, int Nrows, int t) {
    constexpr int R = MI * 16;                 // rows in this tile
    constexpr int KP = K + 8, N1P = N1 + 8;
    constexpr int CPW1 = N1 / 4;
    constexpr int JT1 = CPW1 / 16;
    constexpr int KK1 = K / 32;
    constexpr int KK2 = N1 / 32;
    constexpr int JT2 = N2 / 64;
    constexpr int TPR = 256 / R;               // threads per staged row
    constexpr int FPT = K / TPR;               // floats per thread
    constexpr int F4 = FPT / 4;

    const int tid = threadIdx.x;
    const int wave = tid >> 6, lane = tid & 63;
    const int l15 = lane & 15, quad = lane >> 4;
    const int r0 = t * R;

    {
        int m0 = tid / TPR, pp = tid % TPR;
        int rowg = r0 + m0; if (rowg >= Nrows) rowg = Nrows - 1;
        const float4* src = (const float4*)(x + (long)rowg * K + pp * FPT);
        unsigned short* dst = &sm.sS[m0 * KP + pp * FPT];
#pragma unroll
        for (int u = 0; u < F4; ++u) {
            float4 f = src[u];
            ushort4 h; h.x = f2bf(f.x); h.y = f2bf(f.y); h.z = f2bf(f.z); h.w = f2bf(f.w);
            *(ushort4*)(dst + 4 * u) = h;
        }
    }

    // resident W1 fragments + per-lane params (overlap with staging latency)
    short8 breg1[JT1][KK1];
#pragma unroll
    for (int j = 0; j < JT1; ++j)
#pragma unroll
        for (int kk = 0; kk < KK1; ++kk) {
            int k0 = kk * 32 + quad * 8, n = CPW1 * wave + 16 * j + l15;
            if constexpr (PK) breg1[j][kk] = load_bfrag_pk((const unsigned short*)w1v, k0, n, K);
            else              breg1[j][kk] = load_bfrag((const float*)w1v, k0, n, N1);
        }

    float b1v[JT1], gv[JT1], bev[JT1];
#pragma unroll
    for (int j = 0; j < JT1; ++j) {
        int c = CPW1 * wave + 16 * j + l15;
        b1v[j] = b1[c]; gv[j] = g[c]; bev[j] = be[c];
    }
    float b2v[JT2];
#pragma unroll
    for (int j = 0; j < JT2; ++j) b2v[j] = b2[wave * 16 * JT2 + 16 * j + l15];

    __syncthreads();                           // A ready

    f32x4 acc1[MI][JT1];
#pragma unroll
    for (int i = 0; i < MI; ++i)
#pragma unroll
        for (int j = 0; j < JT1; ++j)
            acc1[i][j] = (f32x4){0.f, 0.f, 0.f, 0.f};

#pragma unroll
    for (int kk = 0; kk < KK1; ++kk) {
        short8 a[MI];
#pragma unroll
        for (int i = 0; i < MI; ++i)
            a[i] = *(const short8*)&sm.sS[(16 * i + l15) * KP + kk * 32 + quad * 8];
#pragma unroll
        for (int i = 0; i < MI; ++i)
#pragma unroll
            for (int j = 0; j < JT1; ++j)
                acc1[i][j] = MFMA(a[i], breg1[j][kk], acc1[i][j]);
    }

#pragma unroll
    for (int i = 0; i < MI; ++i)
#pragma unroll
        for (int r = 0; r < 4; ++r) {
            float s = 0.f, ss = 0.f;
#pragma unroll
            for (int j = 0; j < JT1; ++j) {
                float v = acc1[i][j][r] + b1v[j];
                acc1[i][j][r] = v;
                s += v; ss = __builtin_fmaf(v, v, ss);
            }
            s = rowsum16(s); ss = rowsum16(ss);
            if (l15 == 0) {
                int row = 16 * i + quad * 4 + r;
                *(float2*)&sm.rstat[row * 8 + wave * 2] = make_float2(s, ss);
            }
        }
    __syncthreads();                           // partials ready

#pragma unroll
    for (int i = 0; i < MI; ++i)
#pragma unroll
        for (int r = 0; r < 4; ++r) {
            int row = 16 * i + quad * 4 + r;
            const float4* st = (const float4*)&sm.rstat[row * 8];
            float4 q0 = st[0], q1 = st[1];
            float s  = (q0.x + q0.z) + (q1.x + q1.z);
            float ss = (q0.y + q0.w) + (q1.y + q1.w);
            float mean = s * (1.f / (float)N1);
            float var  = __builtin_fmaf(ss, 1.f / (float)N1, -mean * mean);
            float rstd = __builtin_amdgcn_rsqf(var + 1e-5f);
            float nm = -mean * rstd;
#pragma unroll
            for (int j = 0; j < JT1; ++j) {
                float tt = __builtin_fmaf(acc1[i][j][r], rstd, nm);
                float xn = __builtin_fmaf(tt, gv[j], bev[j]);
                sm.sS[row * N1P + CPW1 * wave + 16 * j + l15] = f2bf(gelu_fast(xn));
            }
        }
    __syncthreads();                           // gelu(h) ready in A-layout

    f32x4 acc2[MI][JT2];
#pragma unroll
    for (int i = 0; i < MI; ++i)
#pragma unroll
        for (int j = 0; j < JT2; ++j)
            acc2[i][j] = (f32x4){0.f, 0.f, 0.f, 0.f};

#pragma unroll
    for (int kk = 0; kk < KK2; ++kk) {
        short8 bf[JT2];
#pragma unroll
        for (int j = 0; j < JT2; ++j) {
            int k0 = kk * 32 + quad * 8, n = wave * 16 * JT2 + 16 * j + l15;
            if constexpr (PK) bf[j] = load_bfrag_pk((const unsigned short*)w2v, k0, n, N1);
            else              bf[j] = load_bfrag((const float*)w2v, k0, n, N2);
        }
        short8 a[MI];
#pragma unroll
        for (int i = 0; i < MI; ++i)
            a[i] = *(const short8*)&sm.sS[(16 * i + l15) * N1P + kk * 32 + quad * 8];
#pragma unroll
        for (int i = 0; i < MI; ++i)
#pragma unroll
            for (int j = 0; j < JT2; ++j)
                acc2[i][j] = MFMA(a[i], bf[j], acc2[i][j]);
    }

#pragma unroll
    for (int i = 0; i < MI; ++i)
#pragma unroll
        for (int r = 0; r < 4; ++r) {
            int rowg = r0 + 16 * i + quad * 4 + r;
            if (rowg < Nrows) {
#pragma unroll
                for (int j = 0; j < JT2; ++j)
                    out[(long)rowg * N2 + wave * 16 * JT2 + 16 * j + l15] = acc2[i][j][r] + b2v[j];
            }
        }
}

// ---------------------------------------------------------------------------
// One proj tile-plane: P = x @ W1half (+ b1 for A-plane), bf16 [N][256] in the
// PERMUTED column layout (slot wave*64+l15*4+j holds logical col
// wave*64+16*j+l15) -> one dwordx2 store per (i,r), fully contiguous.
// ---------------------------------------------------------------------------
template<bool PK>
__device__ void proj_tile(unsigned short* sX /*64*72*/, const float* __restrict__ x,
                          const void* __restrict__ w1v, const float* __restrict__ b1,
                          unsigned short* __restrict__ P, int N, int tile, int isB) {
    constexpr int KP = 72;                     // 144B stride -> 2-way alias (free)
    const int tid = threadIdx.x;
    const int wave = tid >> 6, lane = tid & 63;
    const int l15 = lane & 15, quad = lane >> 4;
    const int r0 = tile * 64;

    {
        int m0 = tid >> 2, pp = tid & 3;       // 4 threads/row, 16 floats each
        int rowg = r0 + m0; if (rowg >= N) rowg = N - 1;
        const float4* src = (const float4*)(x + (long)rowg * 64 + pp * 16);
        unsigned short* dst = &sX[m0 * KP + pp * 16];
#pragma unroll
        for (int u = 0; u < 4; ++u) {
            float4 f = src[u];
            ushort4 h; h.x = f2bf(f.x); h.y = f2bf(f.y); h.z = f2bf(f.z); h.w = f2bf(f.w);
            *(ushort4*)(dst + 4 * u) = h;
        }
    }

    short8 breg[4][2];
#pragma unroll
    for (int j = 0; j < 4; ++j)
#pragma unroll
        for (int kk = 0; kk < 2; ++kk) {
            int k0 = isB * 64 + kk * 32 + quad * 8, n = wave * 64 + 16 * j + l15;
            if constexpr (PK) breg[j][kk] = load_bfrag_pk((const unsigned short*)w1v, k0, n, 128);
            else              breg[j][kk] = load_bfrag((const float*)w1v, k0, n, 256);
        }

    float b1v[4];
#pragma unroll
    for (int j = 0; j < 4; ++j)
        b1v[j] = isB ? 0.f : b1[wave * 64 + 16 * j + l15];

    __syncthreads();

    f32x4 acc[4][4];
#pragma unroll
    for (int i = 0; i < 4; ++i)
#pragma unroll
        for (int j = 0; j < 4; ++j)
            acc[i][j] = (f32x4){0.f, 0.f, 0.f, 0.f};

#pragma unroll
    for (int kk = 0; kk < 2; ++kk) {
        short8 a[4];
#pragma unroll
        for (int i = 0; i < 4; ++i)
            a[i] = *(const short8*)&sX[(16 * i + l15) * KP + kk * 32 + quad * 8];
#pragma unroll
        for (int i = 0; i < 4; ++i)
#pragma unroll
            for (int j = 0; j < 4; ++j)
                acc[i][j] = MFMA(a[i], breg[j][kk], acc[i][j]);
    }

#pragma unroll
    for (int i = 0; i < 4; ++i)
#pragma unroll
        for (int r = 0; r < 4; ++r) {
            int rowg = r0 + 16 * i + quad * 4 + r;     // C/D: row = quad*4+reg
            if (rowg < N) {
                uint2 d;
                d.x = cvt_pk_bf16(acc[i][0][r] + b1v[0], acc[i][1][r] + b1v[1]);
                d.y = cvt_pk_bf16(acc[i][2][r] + b1v[2], acc[i][3][r] + b1v[3]);
                *(uint2*)(P + (long)rowg * 256 + wave * 64 + l15 * 4) = d;
            }
        }
}

// ---------------------------------------------------------------------------
// Edge role: per wave 4 edges (one per 16-lane quad), 16 cols/lane, f32x2
// packed math. 2-deep SW pipeline. R10: int index arithmetic (E<2^31) and
// callers oversubscribe the grid (4096 blocks) at launch_bounds(256,8).
// ---------------------------------------------------------------------------
__device__ __forceinline__ int clamp_e(int v, int E) {
    return v < E ? v : E - 1;
}

__device__ void edge_role2(const unsigned short* __restrict__ Pa,
                           const unsigned short* __restrict__ Pb,
                           const int* __restrict__ ei,
                           const float* __restrict__ g, const float* __restrict__ be,
                           const float* __restrict__ w2, const float* __restrict__ b2,
                           float* __restrict__ out, int E, int ebid, int nebk) {
    const int tid = threadIdx.x;
    const int lane = tid & 63;
    const int quad = lane >> 4, l15 = lane & 15;

    // per-lane params for storage slots l15*16+u under the proj permutation:
    // logical col = (l15>>2)*64 + (u&3)*16 + (l15&3)*4 + (u>>2); packed pairs.
    f32x2 gv2[8], bev2[8], w2v2[8];
#pragma unroll
    for (int k = 0; k < 8; ++k) {
#pragma unroll
        for (int h = 0; h < 2; ++h) {
            int u = 2 * k + h;
            int c = ((l15 >> 2) << 6) + ((u & 3) << 4) + ((l15 & 3) << 2) + (u >> 2);
            gv2[k][h] = g[c]; bev2[k][h] = be[c]; w2v2[k][h] = w2[c];
        }
    }
    const float b2v = b2[0];

    const int wid = ebid * 4 + (tid >> 6);
    const int stride = nebk * 16;              // nebk blocks * 4 waves * 4 edges
    int base = wid * 4;
    if (base >= E) return;

    // pipeline prologue: rows for iter 0, indices for iter 1
    int ir1, ic1;
    uint4 cA0, cA1, cB0, cB1;
    {
        int e0 = clamp_e(base + quad, E);
        int r = ei[e0], c = ei[E + e0];
        const uint4* pa = (const uint4*)(Pa + (long)r * 256 + l15 * 16);
        const uint4* pb = (const uint4*)(Pb + (long)c * 256 + l15 * 16);
        cA0 = pa[0]; cA1 = pa[1]; cB0 = pb[0]; cB1 = pb[1];
        int e1 = clamp_e(base + stride + quad, E);
        ir1 = ei[e1]; ic1 = ei[E + e1];
    }

    for (; base < E; base += stride) {
        int e2 = clamp_e(base + 2 * stride + quad, E);
        int ir2 = ei[e2];
        int ic2 = ei[E + e2];
        const uint4* pa = (const uint4*)(Pa + (long)ir1 * 256 + l15 * 16);
        const uint4* pb = (const uint4*)(Pb + (long)ic1 * 256 + l15 * 16);
        uint4 nA0 = pa[0], nA1 = pa[1], nB0 = pb[0], nB1 = pb[1];

        unsigned int av[8] = {cA0.x, cA0.y, cA0.z, cA0.w, cA1.x, cA1.y, cA1.z, cA1.w};
        unsigned int bv[8] = {cB0.x, cB0.y, cB0.z, cB0.w, cB1.x, cB1.y, cB1.z, cB1.w};

        f32x2 h2[8];
        f32x2 s2 = {0.f, 0.f}, ss2 = {0.f, 0.f};
#pragma unroll
        for (int k = 0; k < 8; ++k) {
            h2[k] = unpk_bf2(av[k]) + unpk_bf2(bv[k]);
            s2 = s2 + h2[k];
            ss2 = __builtin_elementwise_fma(h2[k], h2[k], ss2);
        }
        float s = s2[0] + s2[1], ss = ss2[0] + ss2[1];
        s = rowsum16(s); ss = rowsum16(ss);

        float mean = s * (1.f / 256.f);
        float var  = __builtin_fmaf(ss, 1.f / 256.f, -mean * mean);
        float rstd = __builtin_amdgcn_rsqf(var + 1e-5f);
        float nm = -mean * rstd;
        f32x2 rstd2 = {rstd, rstd}, nm2 = {nm, nm};

        f32x2 spp2 = {0.f, 0.f};
#pragma unroll
        for (int k = 0; k < 8; ++k) {
            f32x2 tt = __builtin_elementwise_fma(h2[k], rstd2, nm2);
            f32x2 xn = __builtin_elementwise_fma(tt, gv2[k], bev2[k]);
            spp2 = __builtin_elementwise_fma(gelu_fast2(xn), w2v2[k], spp2);
        }
        float spp = rowsum16(spp2[0] + spp2[1]);
        int eL = base + quad;
        if (l15 == 0 && eL < E) out[eL] = spp + b2v;

        cA0 = nA0; cA1 = nA1; cB0 = nB0; cB1 = nB1;
        ir1 = ir2; ic1 = ic2;
    }
}

// =============================== R10 kernels ================================
// repack: all five weights -> bf16 8-row panels in fragment order.
__global__ __launch_bounds__(256)
void repack_kernel(const float* __restrict__ sp_w1, const float* __restrict__ fr_w1,
                   const float* __restrict__ fr_w2, const float* __restrict__ ph_w1,
                   const float* __restrict__ ph_w2, unsigned short* __restrict__ wp) {
    int e = blockIdx.x * 256 + threadIdx.x;
    const float* src; unsigned short* dst; int K, Nn;
    if (e < 32768)      { src = sp_w1; dst = wp;         K = 128; Nn = 256; }
    else if (e < 40960) { src = fr_w1; dst = wp + 32768; K = 64;  Nn = 128; e -= 32768; }
    else if (e < 49152) { src = fr_w2; dst = wp + 40960; K = 128; Nn = 64;  e -= 40960; }
    else if (e < 65536) { src = ph_w1; dst = wp + 49152; K = 64;  Nn = 256; e -= 49152; }
    else if (e < 98304) { src = ph_w2; dst = wp + 65536; K = 256; Nn = 128; e -= 65536; }
    else return;
    int n = e / K, k = e % K;
    dst[(n * (K >> 3) + (k >> 3)) * 8 + (k & 7)] = f2bf(src[k * Nn + n]);
}

union SmemPrep {
    unsigned short sX[64 * 72];
    SmemMlp<64, 136> a;                // FR: N1=128
    SmemMlp<32, 264> b;                // PH: N1=256
};

// prep: one tile per block (R5/R7 proven structure), PACKED weight loads.
template<bool PK>
__global__ __launch_bounds__(256)
void prep_kernel(const float* __restrict__ x,
                 const void* __restrict__ sp_w1, const float* __restrict__ sp_b1,
                 const void* __restrict__ fr_w1, const float* __restrict__ fr_b1,
                 const float* __restrict__ fr_g, const float* __restrict__ fr_be,
                 const void* __restrict__ fr_w2, const float* __restrict__ fr_b2,
                 const void* __restrict__ ph_w1, const float* __restrict__ ph_b1,
                 const float* __restrict__ ph_g, const float* __restrict__ ph_be,
                 const void* __restrict__ ph_w2, const float* __restrict__ ph_b2,
                 unsigned short* __restrict__ Pa, unsigned short* __restrict__ Pb,
                 float* __restrict__ out_rec, float* __restrict__ out_proj,
                 int N, int ntN, int nFR, int nPH) {
    __shared__ SmemPrep sm;
    const int b = blockIdx.x;
    if (b < nPH) {
        mlp_tile<64, 256, 128, 2, PK>(sm.b, x, ph_w1, ph_b1, ph_g, ph_be, ph_w2, ph_b2,
                                      out_proj, N, b);
    } else if (b < nPH + nFR) {
        mlp_tile<64, 128, 64, 4, PK>(sm.a, x, fr_w1, fr_b1, fr_g, fr_be, fr_w2, fr_b2,
                                     out_rec, N, b - nPH);
    } else {
        int q = b - nPH - nFR;
        int isB = q >= ntN;
        int tile = isB ? q - ntN : q;
        proj_tile<PK>(sm.sX, x, sp_w1, sp_b1, isB ? Pb : Pa, N, tile, isB);
    }
}

// edge: standalone, no LDS. R10: launch_bounds(256,8) caps VGPR at 64 so 8
// blocks/CU are eligible; grid 4096 (2x capacity) lets the scheduler backfill
// unevenly-drained CUs (R5-R9 showed Occupancy ~36% at exactly-capacity 2048).
__global__ __launch_bounds__(256, 8)
void edge_stream(const unsigned short* __restrict__ Pa, const unsigned short* __restrict__ Pb,
                 const int* __restrict__ ei,
                 const float* __restrict__ g, const float* __restrict__ be,
                 const float* __restrict__ w2, const float* __restrict__ b2,
                 float* __restrict__ out, int E) {
    edge_role2(Pa, Pb, ei, g, be, w2, b2, out, E, blockIdx.x, gridDim.x);
}

// ======================= fallback (ws too small) ============================
struct SmemEdge {
    unsigned short sA[2][32 * 136];
    float rstat[32 * 8];
    float spL[32 * 4];
};
union SmemU {
    SmemEdge e;
    SmemMlp<64, 136> a;
    SmemMlp<32, 264> b;
};

__device__ void edge_role(SmemEdge& sm, const float* __restrict__ x, const int* __restrict__ ei,
                          const float* __restrict__ w1, const float* __restrict__ b1,
                          const float* __restrict__ g, const float* __restrict__ be,
                          const float* __restrict__ w2, const float* __restrict__ b2,
                          float* __restrict__ out, int E, int bid, int nblocks) {
    constexpr int KP = 136;
    const int tid = threadIdx.x;
    const int cw = tid >> 6, lane = tid & 63;
    const int l15 = lane & 15, quad = lane >> 4;

    short8 breg[4][4];
#pragma unroll
    for (int j = 0; j < 4; ++j)
#pragma unroll
        for (int kk = 0; kk < 4; ++kk)
            breg[j][kk] = load_bfrag(w1, kk * 32 + quad * 8, cw * 64 + 16 * j + l15, 256);

    float b1v[4], gv[4], bev[4], w2v[4];
#pragma unroll
    for (int j = 0; j < 4; ++j) {
        int c = cw * 64 + 16 * j + l15;
        b1v[j] = b1[c]; gv[j] = g[c]; bev[j] = be[c]; w2v[j] = w2[c];
    }
    const float b2v = b2[0];

    const int ntiles = (E + 31) >> 5;
    const int eLoc = tid >> 3, p = tid & 7;
    const int node = p >> 2, foff = (p & 3) * 16;

    float4 pf[4];
    auto issue = [&](int t) {
        int e = t * 32 + eLoc; if (e >= E) e = E - 1;
        int idx = ei[node * E + e];
        const float4* src = (const float4*)(x + (long)idx * 64 + foff);
#pragma unroll
        for (int u = 0; u < 4; ++u) pf[u] = src[u];
    };
    auto stage = [&](int buf) {
        unsigned short* dst = &sm.sA[buf][eLoc * KP + node * 64 + foff];
#pragma unroll
        for (int u = 0; u < 4; ++u) {
            ushort4 h;
            h.x = f2bf(pf[u].x); h.y = f2bf(pf[u].y);
            h.z = f2bf(pf[u].z); h.w = f2bf(pf[u].w);
            *(ushort4*)(dst + 4 * u) = h;
        }
    };

    int t = bid;
    if (t >= ntiles) return;
    issue(t); stage(0);
    if (t + nblocks < ntiles) issue(t + nblocks);
    __syncthreads();
    int cur = 0;

    for (; t < ntiles; t += nblocks) {
        f32x4 acc[2][4];
#pragma unroll
        for (int i = 0; i < 2; ++i)
#pragma unroll
            for (int j = 0; j < 4; ++j)
                acc[i][j] = (f32x4){0.f, 0.f, 0.f, 0.f};

#pragma unroll
        for (int kk = 0; kk < 4; ++kk) {
            short8 a[2];
#pragma unroll
            for (int i = 0; i < 2; ++i)
                a[i] = *(const short8*)&sm.sA[cur][(16 * i + l15) * KP + kk * 32 + quad * 8];
#pragma unroll
            for (int i = 0; i < 2; ++i)
#pragma unroll
                for (int j = 0; j < 4; ++j)
                    acc[i][j] = MFMA(a[i], breg[j][kk], acc[i][j]);
        }

        if (t + nblocks < ntiles) {
            stage(cur ^ 1);
            if (t + 2 * nblocks < ntiles) issue(t + 2 * nblocks);
        }

#pragma unroll
        for (int i = 0; i < 2; ++i)
#pragma unroll
            for (int r = 0; r < 4; ++r) {
                float v0 = acc[i][0][r] + b1v[0];
                float v1 = acc[i][1][r] + b1v[1];
                float v2 = acc[i][2][r] + b1v[2];
                float v3 = acc[i][3][r] + b1v[3];
                acc[i][0][r] = v0; acc[i][1][r] = v1; acc[i][2][r] = v2; acc[i][3][r] = v3;
                float s  = (v0 + v1) + (v2 + v3);
                float ss = __builtin_fmaf(v0, v0, __builtin_fmaf(v1, v1,
                           __builtin_fmaf(v2, v2, v3 * v3)));
                s = rowsum16(s); ss = rowsum16(ss);
                if (l15 == 0) {
                    int row = 16 * i + quad * 4 + r;
                    *(float2*)&sm.rstat[row * 8 + cw * 2] = make_float2(s, ss);
                }
            }
        __syncthreads();

#pragma unroll
        for (int i = 0; i < 2; ++i)
#pragma unroll
            for (int r = 0; r < 4; ++r) {
                int row = 16 * i + quad * 4 + r;
                const float4* st = (const float4*)&sm.rstat[row * 8];
                float4 q0 = st[0], q1 = st[1];
                float s  = (q0.x + q0.z) + (q1.x + q1.z);
                float ss = (q0.y + q0.w) + (q1.y + q1.w);
                float mean = s * (1.f / 256.f);
                float var  = __builtin_fmaf(ss, 1.f / 256.f, -mean * mean);
                float rstd = __builtin_amdgcn_rsqf(var + 1e-5f);
                float nm = -mean * rstd;
                float spp = 0.f;
#pragma unroll
                for (int j = 0; j < 4; ++j) {
                    float tt = __builtin_fmaf(acc[i][j][r], rstd, nm);
                    float xn = __builtin_fmaf(tt, gv[j], bev[j]);
                    spp = __builtin_fmaf(gelu_fast(xn), w2v[j], spp);
                }
                spp = rowsum16(spp);
                if (l15 == 0) sm.spL[row * 4 + cw] = spp;
            }
        __syncthreads();

        if (tid < 32) {
            int e = t * 32 + tid;
            if (e < E) {
                const float4* sp = (const float4*)&sm.spL[tid * 4];
                float4 u0 = sp[0];
                out[e] = ((u0.x + u0.y) + (u0.z + u0.w)) + b2v;
            }
        }
        cur ^= 1;
    }
}

__global__ __launch_bounds__(256, 3)
void fused_all(const float* __restrict__ x, const int* __restrict__ ei,
               const float* __restrict__ sp_w1, const float* __restrict__ sp_b1,
               const float* __restrict__ sp_g, const float* __restrict__ sp_be,
               const float* __restrict__ sp_w2, const float* __restrict__ sp_b2,
               const float* __restrict__ fr_w1, const float* __restrict__ fr_b1,
               const float* __restrict__ fr_g, const float* __restrict__ fr_be,
               const float* __restrict__ fr_w2, const float* __restrict__ fr_b2,
               const float* __restrict__ ph_w1, const float* __restrict__ ph_b1,
               const float* __restrict__ ph_g, const float* __restrict__ ph_be,
               const float* __restrict__ ph_w2, const float* __restrict__ ph_b2,
               float* __restrict__ out_sp, float* __restrict__ out_rec,
               float* __restrict__ out_proj, int N, int E) {
    __shared__ SmemU sm;
    const int b = blockIdx.x;
    if (b < 128) {
        for (int tt = b; tt < (N + 63) / 64; tt += 128) {
            __syncthreads();
            mlp_tile<64, 128, 64, 4, false>(sm.a, x, fr_w1, fr_b1, fr_g, fr_be, fr_w2, fr_b2,
                                            out_rec, N, tt);
        }
    } else if (b < 256) {
        for (int tt = b - 128; tt < (N + 31) / 32; tt += 128) {
            __syncthreads();
            mlp_tile<64, 256, 128, 2, false>(sm.b, x, ph_w1, ph_b1, ph_g, ph_be, ph_w2, ph_b2,
                                             out_proj, N, tt);
        }
    } else {
        edge_role(sm.e, x, ei, sp_w1, sp_b1, sp_g, sp_be, sp_w2, sp_b2,
                  out_sp, E, b - 256, 1024);
    }
}
// ===========================================================================

extern "C" void kernel_launch(void* const* d_in, const int* in_sizes, int n_in,
                              void* d_out, int out_size, void* d_ws, size_t ws_size,
                              hipStream_t stream) {
    const float* x     = (const float*)d_in[0];
    const int*   ei    = (const int*)d_in[1];
    const float* sp_w1 = (const float*)d_in[2];
    const float* sp_b1 = (const float*)d_in[3];
    const float* sp_g  = (const float*)d_in[4];
    const float* sp_be = (const float*)d_in[5];
    const float* sp_w2 = (const float*)d_in[6];
    const float* sp_b2 = (const float*)d_in[7];
    const float* fr_w1 = (const float*)d_in[8];
    const float* fr_b1 = (const float*)d_in[9];
    const float* fr_g  = (const float*)d_in[10];
    const float* fr_be = (const float*)d_in[11];
    const float* fr_w2 = (const float*)d_in[12];
    const float* fr_b2 = (const float*)d_in[13];
    const float* ph_w1 = (const float*)d_in[14];
    const float* ph_b1 = (const float*)d_in[15];
    const float* ph_g  = (const float*)d_in[16];
    const float* ph_be = (const float*)d_in[17];
    const float* ph_w2 = (const float*)d_in[18];
    const float* ph_b2 = (const float*)d_in[19];

    const int N = in_sizes[0] / 64;
    const int E = in_sizes[1] / 2;

    float* out_sp   = (float*)d_out;
    float* out_rec  = out_sp + E;
    float* out_proj = out_rec + (size_t)N * 64;

    const size_t pbytes  = 2ull * (size_t)N * 256 * sizeof(unsigned short);
    const size_t wbytes  = 98304 * sizeof(unsigned short);   // packed weights
    const size_t needed  = pbytes;
    const size_t needed2 = pbytes + wbytes;

    const int ntN = (N + 63) / 64;             // proj tiles per plane
    const int nFR = (N + 63) / 64;             // FR tiles (64-row)
    const int nPH = (N + 31) / 32;             // PH tiles (32-row)

    if (ws_size >= needed2) {
        unsigned short* wp = (unsigned short*)d_ws;
        unsigned short* Pa = wp + 98304;
        unsigned short* Pb = Pa + (size_t)N * 256;
        const unsigned short* wp_sp  = wp;
        const unsigned short* wp_fr1 = wp + 32768;
        const unsigned short* wp_fr2 = wp + 40960;
        const unsigned short* wp_ph1 = wp + 49152;
        const unsigned short* wp_ph2 = wp + 65536;

        repack_kernel<<<dim3(384), dim3(256), 0, stream>>>(
            sp_w1, fr_w1, fr_w2, ph_w1, ph_w2, wp);

        prep_kernel<true><<<dim3(nPH + nFR + 2 * ntN), dim3(256), 0, stream>>>(
            x, wp_sp, sp_b1,
            wp_fr1, fr_b1, fr_g, fr_be, wp_fr2, fr_b2,
            wp_ph1, ph_b1, ph_g, ph_be, wp_ph2, ph_b2,
            Pa, Pb, out_rec, out_proj, N, ntN, nFR, nPH);

        edge_stream<<<dim3(4096), dim3(256), 0, stream>>>(
            Pa, Pb, ei, sp_g, sp_be, sp_w2, sp_b2, out_sp, E);
    } else if (ws_size >= needed) {
        unsigned short* Pa = (unsigned short*)d_ws;
        unsigned short* Pb = Pa + (size_t)N * 256;

        prep_kernel<false><<<dim3(nPH + nFR + 2 * ntN), dim3(256), 0, stream>>>(
            x, sp_w1, sp_b1,
            fr_w1, fr_b1, fr_g, fr_be, fr_w2, fr_b2,
            ph_w1, ph_b1, ph_g, ph_be, ph_w2, ph_b2,
            Pa, Pb, out_rec, out_proj, N, ntN, nFR, nPH);

        edge_stream<<<dim3(4096), dim3(256), 0, stream>>>(
            Pa, Pb, ei, sp_g, sp_be, sp_w2, sp_b2, out_sp, E);
    } else {
        fused_all<<<dim3(1280), dim3(256), 0, stream>>>(
            x, ei, sp_w1, sp_b1, sp_g, sp_be, sp_w2, sp_b2,
            fr_w1, fr_b1, fr_g, fr_be, fr_w2, fr_b2,
            ph_w1, ph_b1, ph_g, ph_be, ph_w2, ph_b2,
            out_sp, out_rec, out_proj, N, E);
    }
}

// Round 11
// 256.944 us; speedup vs baseline: 1.8485x; 1.8485x over previous
//
#include <hip/hip_runtime.h>
#include <hip/hip_bf16.h>

typedef __attribute__((ext_vector_type(8))) short short8;   // 8 bf16 = 4 VGPRs (MFMA A/B frag)
typedef __attribute__((ext_vector_type(4))) float f32x4;    // MFMA C/D frag
typedef __attribute__((ext_vector_type(2))) float f32x2;    // packed-f32 (v_pk_*) pair

#define MFMA(a, b, c) __builtin_amdgcn_mfma_f32_16x16x32_bf16((a), (b), (c), 0, 0, 0)

__device__ __forceinline__ unsigned short f2bf(float f) {
    unsigned int u = __float_as_uint(f);
    u += 0x7fffu + ((u >> 16) & 1u);          // round-to-nearest-even
    return (unsigned short)(u >> 16);
}

// pack two f32 -> one u32 of 2x bf16 (RNE), single instruction
__device__ __forceinline__ unsigned int cvt_pk_bf16(float lo, float hi) {
    unsigned int d;
    asm("v_cvt_pk_bf16_f32 %0, %1, %2" : "=v"(d) : "v"(lo), "v"(hi));
    return d;
}

// 16-lane sum via DPP row_ror (VALU-only). Each 16-lane row gets its full sum.
template<int CTRL>
__device__ __forceinline__ float dpp_addf(float v) {
    int t = __builtin_amdgcn_update_dpp(0, __float_as_int(v), CTRL, 0xF, 0xF, true);
    return v + __int_as_float(t);
}
__device__ __forceinline__ float rowsum16(float v) {
    v = dpp_addf<0x121>(v);   // row_ror:1
    v = dpp_addf<0x122>(v);   // row_ror:2
    v = dpp_addf<0x124>(v);   // row_ror:4
    v = dpp_addf<0x128>(v);   // row_ror:8
    return v;
}

#if __has_builtin(__builtin_amdgcn_exp2f)
#define EXP2(x) __builtin_amdgcn_exp2f(x)
#else
#define EXP2(x) __expf((x) * 0.69314718f)
#endif

// gelu tanh-form: x*E/(E+1) = x - x/(E+1), E=exp2(x*(2.3021210+0.10295427 x^2)).
__device__ __forceinline__ float gelu_fast(float x) {
    float a = x * __builtin_fmaf(x * x, 0.10295427f, 2.3021210f);
    float E = EXP2(a);
    float r = __builtin_amdgcn_rcpf(E + 1.0f);
    return __builtin_fmaf(-x, r, x);          // x*E/(E+1)
}

// packed (2-wide) gelu for the edge stream
__device__ __forceinline__ f32x2 gelu_fast2(f32x2 x) {
    f32x2 c1 = {2.3021210f, 2.3021210f}, c2 = {0.10295427f, 0.10295427f};
    f32x2 a = x * __builtin_elementwise_fma(x * x, c2, c1);
    f32x2 E;
    E[0] = EXP2(a[0]); E[1] = EXP2(a[1]);
    f32x2 Ep = E + (f32x2){1.f, 1.f};
    f32x2 r;
    r[0] = __builtin_amdgcn_rcpf(Ep[0]); r[1] = __builtin_amdgcn_rcpf(Ep[1]);
    return __builtin_elementwise_fma(-x, r, x);
}

// unpack u32 of 2 bf16 -> f32x2 {lo, hi}
__device__ __forceinline__ f32x2 unpk_bf2(unsigned int a) {
    f32x2 r;
    r[0] = __uint_as_float(a << 16);
    r[1] = __uint_as_float(a & 0xffff0000u);
    return r;
}

// ---- weight fragment loaders --------------------------------------------
// scalar fallback: 8 strided f32 loads + converts
__device__ __forceinline__ short8 load_bfrag(const float* __restrict__ w, int k0, int n, int ldn) {
    short8 r;
#pragma unroll
    for (int u = 0; u < 8; ++u)
        r[u] = (short)f2bf(w[(k0 + u) * ldn + n]);
    return r;
}
// packed: ONE 16B load. WP[(n*(krows/8) + k0/8)*8 + u] = bf16(W[k0+u][n]).
__device__ __forceinline__ short8 load_bfrag_pk(const unsigned short* __restrict__ wp,
                                                int k0, int n, int krows) {
    return *(const short8*)&wp[(n * (krows >> 3) + (k0 >> 3)) << 3];
}

template<int R, int N1P>
struct SmemMlp {
    unsigned short sS[R * N1P];      // union: A [R][K+8] then gelu(h) [R][N1P]
    float rstat[R * 8];
};

// ---------------------------------------------------------------------------
// One MLP-head tile: out = gelu(LN(x@W1+b1)*g+be) @ W2 + b2 for MI*16 rows.
// 4 waves cooperative, fully unrolled. R5-proven tile sizes (FR MI=4, PH MI=2).
// ---------------------------------------------------------------------------
template<int K, int N1, int N2, int MI, bool PK>
__device__ void mlp_tile(SmemMlp<MI * 16, N1 + 8>& sm, const float* __restrict__ x,
                         const void* __restrict__ w1v, const float* __restrict__ b1,
                         const float* __restrict__ g, const float* __restrict__ be,
                         const void* __restrict__ w2v, const float* __restrict__ b2,
                         float* __restrict__ out, int Nrows, int t) {
    constexpr int R = MI * 16;                 // rows in this tile
    constexpr int KP = K + 8, N1P = N1 + 8;
    constexpr int CPW1 = N1 / 4;
    constexpr int JT1 = CPW1 / 16;
    constexpr int KK1 = K / 32;
    constexpr int KK2 = N1 / 32;
    constexpr int JT2 = N2 / 64;
    constexpr int TPR = 256 / R;               // threads per staged row
    constexpr int FPT = K / TPR;               // floats per thread
    constexpr int F4 = FPT / 4;

    const int tid = threadIdx.x;
    const int wave = tid >> 6, lane = tid & 63;
    const int l15 = lane & 15, quad = lane >> 4;
    const int r0 = t * R;

    {
        int m0 = tid / TPR, pp = tid % TPR;
        int rowg = r0 + m0; if (rowg >= Nrows) rowg = Nrows - 1;
        const float4* src = (const float4*)(x + (long)rowg * K + pp * FPT);
        unsigned short* dst = &sm.sS[m0 * KP + pp * FPT];
#pragma unroll
        for (int u = 0; u < F4; ++u) {
            float4 f = src[u];
            ushort4 h; h.x = f2bf(f.x); h.y = f2bf(f.y); h.z = f2bf(f.z); h.w = f2bf(f.w);
            *(ushort4*)(dst + 4 * u) = h;
        }
    }

    // resident W1 fragments + per-lane params (overlap with staging latency)
    short8 breg1[JT1][KK1];
#pragma unroll
    for (int j = 0; j < JT1; ++j)
#pragma unroll
        for (int kk = 0; kk < KK1; ++kk) {
            int k0 = kk * 32 + quad * 8, n = CPW1 * wave + 16 * j + l15;
            if constexpr (PK) breg1[j][kk] = load_bfrag_pk((const unsigned short*)w1v, k0, n, K);
            else              breg1[j][kk] = load_bfrag((const float*)w1v, k0, n, N1);
        }

    float b1v[JT1], gv[JT1], bev[JT1];
#pragma unroll
    for (int j = 0; j < JT1; ++j) {
        int c = CPW1 * wave + 16 * j + l15;
        b1v[j] = b1[c]; gv[j] = g[c]; bev[j] = be[c];
    }
    float b2v[JT2];
#pragma unroll
    for (int j = 0; j < JT2; ++j) b2v[j] = b2[wave * 16 * JT2 + 16 * j + l15];

    __syncthreads();                           // A ready

    f32x4 acc1[MI][JT1];
#pragma unroll
    for (int i = 0; i < MI; ++i)
#pragma unroll
        for (int j = 0; j < JT1; ++j)
            acc1[i][j] = (f32x4){0.f, 0.f, 0.f, 0.f};

#pragma unroll
    for (int kk = 0; kk < KK1; ++kk) {
        short8 a[MI];
#pragma unroll
        for (int i = 0; i < MI; ++i)
            a[i] = *(const short8*)&sm.sS[(16 * i + l15) * KP + kk * 32 + quad * 8];
#pragma unroll
        for (int i = 0; i < MI; ++i)
#pragma unroll
            for (int j = 0; j < JT1; ++j)
                acc1[i][j] = MFMA(a[i], breg1[j][kk], acc1[i][j]);
    }

#pragma unroll
    for (int i = 0; i < MI; ++i)
#pragma unroll
        for (int r = 0; r < 4; ++r) {
            float s = 0.f, ss = 0.f;
#pragma unroll
            for (int j = 0; j < JT1; ++j) {
                float v = acc1[i][j][r] + b1v[j];
                acc1[i][j][r] = v;
                s += v; ss = __builtin_fmaf(v, v, ss);
            }
            s = rowsum16(s); ss = rowsum16(ss);
            if (l15 == 0) {
                int row = 16 * i + quad * 4 + r;
                *(float2*)&sm.rstat[row * 8 + wave * 2] = make_float2(s, ss);
            }
        }
    __syncthreads();                           // partials ready

#pragma unroll
    for (int i = 0; i < MI; ++i)
#pragma unroll
        for (int r = 0; r < 4; ++r) {
            int row = 16 * i + quad * 4 + r;
            const float4* st = (const float4*)&sm.rstat[row * 8];
            float4 q0 = st[0], q1 = st[1];
            float s  = (q0.x + q0.z) + (q1.x + q1.z);
            float ss = (q0.y + q0.w) + (q1.y + q1.w);
            float mean = s * (1.f / (float)N1);
            float var  = __builtin_fmaf(ss, 1.f / (float)N1, -mean * mean);
            float rstd = __builtin_amdgcn_rsqf(var + 1e-5f);
            float nm = -mean * rstd;
#pragma unroll
            for (int j = 0; j < JT1; ++j) {
                float tt = __builtin_fmaf(acc1[i][j][r], rstd, nm);
                float xn = __builtin_fmaf(tt, gv[j], bev[j]);
                sm.sS[row * N1P + CPW1 * wave + 16 * j + l15] = f2bf(gelu_fast(xn));
            }
        }
    __syncthreads();                           // gelu(h) ready in A-layout

    f32x4 acc2[MI][JT2];
#pragma unroll
    for (int i = 0; i < MI; ++i)
#pragma unroll
        for (int j = 0; j < JT2; ++j)
            acc2[i][j] = (f32x4){0.f, 0.f, 0.f, 0.f};

#pragma unroll
    for (int kk = 0; kk < KK2; ++kk) {
        short8 bf[JT2];
#pragma unroll
        for (int j = 0; j < JT2; ++j) {
            int k0 = kk * 32 + quad * 8, n = wave * 16 * JT2 + 16 * j + l15;
            if constexpr (PK) bf[j] = load_bfrag_pk((const unsigned short*)w2v, k0, n, N1);
            else              bf[j] = load_bfrag((const float*)w2v, k0, n, N2);
        }
        short8 a[MI];
#pragma unroll
        for (int i = 0; i < MI; ++i)
            a[i] = *(const short8*)&sm.sS[(16 * i + l15) * N1P + kk * 32 + quad * 8];
#pragma unroll
        for (int i = 0; i < MI; ++i)
#pragma unroll
            for (int j = 0; j < JT2; ++j)
                acc2[i][j] = MFMA(a[i], bf[j], acc2[i][j]);
    }

#pragma unroll
    for (int i = 0; i < MI; ++i)
#pragma unroll
        for (int r = 0; r < 4; ++r) {
            int rowg = r0 + 16 * i + quad * 4 + r;
            if (rowg < Nrows) {
#pragma unroll
                for (int j = 0; j < JT2; ++j)
                    out[(long)rowg * N2 + wave * 16 * JT2 + 16 * j + l15] = acc2[i][j][r] + b2v[j];
            }
        }
}

// ---------------------------------------------------------------------------
// One proj tile-plane: P = x @ W1half (+ b1 for A-plane), bf16 [N][256] in the
// PERMUTED column layout (slot wave*64+l15*4+j holds logical col
// wave*64+16*j+l15) -> one dwordx2 store per (i,r), fully contiguous.
// ---------------------------------------------------------------------------
template<bool PK>
__device__ void proj_tile(unsigned short* sX /*64*72*/, const float* __restrict__ x,
                          const void* __restrict__ w1v, const float* __restrict__ b1,
                          unsigned short* __restrict__ P, int N, int tile, int isB) {
    constexpr int KP = 72;                     // 144B stride -> 2-way alias (free)
    const int tid = threadIdx.x;
    const int wave = tid >> 6, lane = tid & 63;
    const int l15 = lane & 15, quad = lane >> 4;
    const int r0 = tile * 64;

    {
        int m0 = tid >> 2, pp = tid & 3;       // 4 threads/row, 16 floats each
        int rowg = r0 + m0; if (rowg >= N) rowg = N - 1;
        const float4* src = (const float4*)(x + (long)rowg * 64 + pp * 16);
        unsigned short* dst = &sX[m0 * KP + pp * 16];
#pragma unroll
        for (int u = 0; u < 4; ++u) {
            float4 f = src[u];
            ushort4 h; h.x = f2bf(f.x); h.y = f2bf(f.y); h.z = f2bf(f.z); h.w = f2bf(f.w);
            *(ushort4*)(dst + 4 * u) = h;
        }
    }

    short8 breg[4][2];
#pragma unroll
    for (int j = 0; j < 4; ++j)
#pragma unroll
        for (int kk = 0; kk < 2; ++kk) {
            int k0 = isB * 64 + kk * 32 + quad * 8, n = wave * 64 + 16 * j + l15;
            if constexpr (PK) breg[j][kk] = load_bfrag_pk((const unsigned short*)w1v, k0, n, 128);
            else              breg[j][kk] = load_bfrag((const float*)w1v, k0, n, 256);
        }

    float b1v[4];
#pragma unroll
    for (int j = 0; j < 4; ++j)
        b1v[j] = isB ? 0.f : b1[wave * 64 + 16 * j + l15];

    __syncthreads();

    f32x4 acc[4][4];
#pragma unroll
    for (int i = 0; i < 4; ++i)
#pragma unroll
        for (int j = 0; j < 4; ++j)
            acc[i][j] = (f32x4){0.f, 0.f, 0.f, 0.f};

#pragma unroll
    for (int kk = 0; kk < 2; ++kk) {
        short8 a[4];
#pragma unroll
        for (int i = 0; i < 4; ++i)
            a[i] = *(const short8*)&sX[(16 * i + l15) * KP + kk * 32 + quad * 8];
#pragma unroll
        for (int i = 0; i < 4; ++i)
#pragma unroll
            for (int j = 0; j < 4; ++j)
                acc[i][j] = MFMA(a[i], breg[j][kk], acc[i][j]);
    }

#pragma unroll
    for (int i = 0; i < 4; ++i)
#pragma unroll
        for (int r = 0; r < 4; ++r) {
            int rowg = r0 + 16 * i + quad * 4 + r;     // C/D: row = quad*4+reg
            if (rowg < N) {
                uint2 d;
                d.x = cvt_pk_bf16(acc[i][0][r] + b1v[0], acc[i][1][r] + b1v[1]);
                d.y = cvt_pk_bf16(acc[i][2][r] + b1v[2], acc[i][3][r] + b1v[3]);
                *(uint2*)(P + (long)rowg * 256 + wave * 64 + l15 * 4) = d;
            }
        }
}

// ---------------------------------------------------------------------------
// Edge role: per wave 4 edges (one per 16-lane quad), 16 cols/lane, f32x2
// packed math. 2-deep SW pipeline. R11: REVERTED to the proven 56-VGPR form
// (R10's launch_bounds(256,8) forced 32 VGPR -> scratch spills, FETCH 3x).
// Only surviving R10 change: int index arithmetic + 4096-block grid.
// ---------------------------------------------------------------------------
__device__ __forceinline__ int clamp_e(int v, int E) {
    return v < E ? v : E - 1;
}

__device__ void edge_role2(const unsigned short* __restrict__ Pa,
                           const unsigned short* __restrict__ Pb,
                           const int* __restrict__ ei,
                           const float* __restrict__ g, const float* __restrict__ be,
                           const float* __restrict__ w2, const float* __restrict__ b2,
                           float* __restrict__ out, int E, int ebid, int nebk) {
    const int tid = threadIdx.x;
    const int lane = tid & 63;
    const int quad = lane >> 4, l15 = lane & 15;

    // per-lane params for storage slots l15*16+u under the proj permutation:
    // logical col = (l15>>2)*64 + (u&3)*16 + (l15&3)*4 + (u>>2); packed pairs.
    f32x2 gv2[8], bev2[8], w2v2[8];
#pragma unroll
    for (int k = 0; k < 8; ++k) {
#pragma unroll
        for (int h = 0; h < 2; ++h) {
            int u = 2 * k + h;
            int c = ((l15 >> 2) << 6) + ((u & 3) << 4) + ((l15 & 3) << 2) + (u >> 2);
            gv2[k][h] = g[c]; bev2[k][h] = be[c]; w2v2[k][h] = w2[c];
        }
    }
    const float b2v = b2[0];

    const int wid = ebid * 4 + (tid >> 6);
    const int stride = nebk * 16;              // nebk blocks * 4 waves * 4 edges
    int base = wid * 4;
    if (base >= E) return;

    // pipeline prologue: rows for iter 0, indices for iter 1
    int ir1, ic1;
    uint4 cA0, cA1, cB0, cB1;
    {
        int e0 = clamp_e(base + quad, E);
        int r = ei[e0], c = ei[E + e0];
        const uint4* pa = (const uint4*)(Pa + (long)r * 256 + l15 * 16);
        const uint4* pb = (const uint4*)(Pb + (long)c * 256 + l15 * 16);
        cA0 = pa[0]; cA1 = pa[1]; cB0 = pb[0]; cB1 = pb[1];
        int e1 = clamp_e(base + stride + quad, E);
        ir1 = ei[e1]; ic1 = ei[E + e1];
    }

    for (; base < E; base += stride) {
        int e2 = clamp_e(base + 2 * stride + quad, E);
        int ir2 = ei[e2];
        int ic2 = ei[E + e2];
        const uint4* pa = (const uint4*)(Pa + (long)ir1 * 256 + l15 * 16);
        const uint4* pb = (const uint4*)(Pb + (long)ic1 * 256 + l15 * 16);
        uint4 nA0 = pa[0], nA1 = pa[1], nB0 = pb[0], nB1 = pb[1];

        unsigned int av[8] = {cA0.x, cA0.y, cA0.z, cA0.w, cA1.x, cA1.y, cA1.z, cA1.w};
        unsigned int bv[8] = {cB0.x, cB0.y, cB0.z, cB0.w, cB1.x, cB1.y, cB1.z, cB1.w};

        f32x2 h2[8];
        f32x2 s2 = {0.f, 0.f}, ss2 = {0.f, 0.f};
#pragma unroll
        for (int k = 0; k < 8; ++k) {
            h2[k] = unpk_bf2(av[k]) + unpk_bf2(bv[k]);
            s2 = s2 + h2[k];
            ss2 = __builtin_elementwise_fma(h2[k], h2[k], ss2);
        }
        float s = s2[0] + s2[1], ss = ss2[0] + ss2[1];
        s = rowsum16(s); ss = rowsum16(ss);

        float mean = s * (1.f / 256.f);
        float var  = __builtin_fmaf(ss, 1.f / 256.f, -mean * mean);
        float rstd = __builtin_amdgcn_rsqf(var + 1e-5f);
        float nm = -mean * rstd;
        f32x2 rstd2 = {rstd, rstd}, nm2 = {nm, nm};

        f32x2 spp2 = {0.f, 0.f};
#pragma unroll
        for (int k = 0; k < 8; ++k) {
            f32x2 tt = __builtin_elementwise_fma(h2[k], rstd2, nm2);
            f32x2 xn = __builtin_elementwise_fma(tt, gv2[k], bev2[k]);
            spp2 = __builtin_elementwise_fma(gelu_fast2(xn), w2v2[k], spp2);
        }
        float spp = rowsum16(spp2[0] + spp2[1]);
        int eL = base + quad;
        if (l15 == 0 && eL < E) out[eL] = spp + b2v;

        cA0 = nA0; cA1 = nA1; cB0 = nB0; cB1 = nB1;
        ir1 = ir2; ic1 = ic2;
    }
}

// =============================== R11 kernels ================================
// repack: all five weights -> bf16 8-row panels in fragment order.
__global__ __launch_bounds__(256)
void repack_kernel(const float* __restrict__ sp_w1, const float* __restrict__ fr_w1,
                   const float* __restrict__ fr_w2, const float* __restrict__ ph_w1,
                   const float* __restrict__ ph_w2, unsigned short* __restrict__ wp) {
    int e = blockIdx.x * 256 + threadIdx.x;
    const float* src; unsigned short* dst; int K, Nn;
    if (e < 32768)      { src = sp_w1; dst = wp;         K = 128; Nn = 256; }
    else if (e < 40960) { src = fr_w1; dst = wp + 32768; K = 64;  Nn = 128; e -= 32768; }
    else if (e < 49152) { src = fr_w2; dst = wp + 40960; K = 128; Nn = 64;  e -= 40960; }
    else if (e < 65536) { src = ph_w1; dst = wp + 49152; K = 64;  Nn = 256; e -= 49152; }
    else if (e < 98304) { src = ph_w2; dst = wp + 65536; K = 256; Nn = 128; e -= 65536; }
    else return;
    int n = e / K, k = e % K;
    dst[(n * (K >> 3) + (k >> 3)) * 8 + (k & 7)] = f2bf(src[k * Nn + n]);
}

union SmemPrep {
    unsigned short sX[64 * 72];
    SmemMlp<64, 136> a;                // FR: N1=128
    SmemMlp<32, 264> b;                // PH: N1=256
};

// prep: one tile per block (R5/R7 proven structure), PACKED weight loads.
template<bool PK>
__global__ __launch_bounds__(256)
void prep_kernel(const float* __restrict__ x,
                 const void* __restrict__ sp_w1, const float* __restrict__ sp_b1,
                 const void* __restrict__ fr_w1, const float* __restrict__ fr_b1,
                 const float* __restrict__ fr_g, const float* __restrict__ fr_be,
                 const void* __restrict__ fr_w2, const float* __restrict__ fr_b2,
                 const void* __restrict__ ph_w1, const float* __restrict__ ph_b1,
                 const float* __restrict__ ph_g, const float* __restrict__ ph_be,
                 const void* __restrict__ ph_w2, const float* __restrict__ ph_b2,
                 unsigned short* __restrict__ Pa, unsigned short* __restrict__ Pb,
                 float* __restrict__ out_rec, float* __restrict__ out_proj,
                 int N, int ntN, int nFR, int nPH) {
    __shared__ SmemPrep sm;
    const int b = blockIdx.x;
    if (b < nPH) {
        mlp_tile<64, 256, 128, 2, PK>(sm.b, x, ph_w1, ph_b1, ph_g, ph_be, ph_w2, ph_b2,
                                      out_proj, N, b);
    } else if (b < nPH + nFR) {
        mlp_tile<64, 128, 64, 4, PK>(sm.a, x, fr_w1, fr_b1, fr_g, fr_be, fr_w2, fr_b2,
                                     out_rec, N, b - nPH);
    } else {
        int q = b - nPH - nFR;
        int isB = q >= ntN;
        int tile = isB ? q - ntN : q;
        proj_tile<PK>(sm.sX, x, sp_w1, sp_b1, isB ? Pb : Pa, N, tile, isB);
    }
}

// edge: standalone, no LDS, plain launch bounds (compiler picks ~56 VGPR, the
// proven no-spill config). Grid 4096 = 2x capacity for scheduler backfill.
__global__ __launch_bounds__(256)
void edge_stream(const unsigned short* __restrict__ Pa, const unsigned short* __restrict__ Pb,
                 const int* __restrict__ ei,
                 const float* __restrict__ g, const float* __restrict__ be,
                 const float* __restrict__ w2, const float* __restrict__ b2,
                 float* __restrict__ out, int E) {
    edge_role2(Pa, Pb, ei, g, be, w2, b2, out, E, blockIdx.x, gridDim.x);
}

// ======================= fallback (ws too small) ============================
struct SmemEdge {
    unsigned short sA[2][32 * 136];
    float rstat[32 * 8];
    float spL[32 * 4];
};
union SmemU {
    SmemEdge e;
    SmemMlp<64, 136> a;
    SmemMlp<32, 264> b;
};

__device__ void edge_role(SmemEdge& sm, const float* __restrict__ x, const int* __restrict__ ei,
                          const float* __restrict__ w1, const float* __restrict__ b1,
                          const float* __restrict__ g, const float* __restrict__ be,
                          const float* __restrict__ w2, const float* __restrict__ b2,
                          float* __restrict__ out, int E, int bid, int nblocks) {
    constexpr int KP = 136;
    const int tid = threadIdx.x;
    const int cw = tid >> 6, lane = tid & 63;
    const int l15 = lane & 15, quad = lane >> 4;

    short8 breg[4][4];
#pragma unroll
    for (int j = 0; j < 4; ++j)
#pragma unroll
        for (int kk = 0; kk < 4; ++kk)
            breg[j][kk] = load_bfrag(w1, kk * 32 + quad * 8, cw * 64 + 16 * j + l15, 256);

    float b1v[4], gv[4], bev[4], w2v[4];
#pragma unroll
    for (int j = 0; j < 4; ++j) {
        int c = cw * 64 + 16 * j + l15;
        b1v[j] = b1[c]; gv[j] = g[c]; bev[j] = be[c]; w2v[j] = w2[c];
    }
    const float b2v = b2[0];

    const int ntiles = (E + 31) >> 5;
    const int eLoc = tid >> 3, p = tid & 7;
    const int node = p >> 2, foff = (p & 3) * 16;

    float4 pf[4];
    auto issue = [&](int t) {
        int e = t * 32 + eLoc; if (e >= E) e = E - 1;
        int idx = ei[node * E + e];
        const float4* src = (const float4*)(x + (long)idx * 64 + foff);
#pragma unroll
        for (int u = 0; u < 4; ++u) pf[u] = src[u];
    };
    auto stage = [&](int buf) {
        unsigned short* dst = &sm.sA[buf][eLoc * KP + node * 64 + foff];
#pragma unroll
        for (int u = 0; u < 4; ++u) {
            ushort4 h;
            h.x = f2bf(pf[u].x); h.y = f2bf(pf[u].y);
            h.z = f2bf(pf[u].z); h.w = f2bf(pf[u].w);
            *(ushort4*)(dst + 4 * u) = h;
        }
    };

    int t = bid;
    if (t >= ntiles) return;
    issue(t); stage(0);
    if (t + nblocks < ntiles) issue(t + nblocks);
    __syncthreads();
    int cur = 0;

    for (; t < ntiles; t += nblocks) {
        f32x4 acc[2][4];
#pragma unroll
        for (int i = 0; i < 2; ++i)
#pragma unroll
            for (int j = 0; j < 4; ++j)
                acc[i][j] = (f32x4){0.f, 0.f, 0.f, 0.f};

#pragma unroll
        for (int kk = 0; kk < 4; ++kk) {
            short8 a[2];
#pragma unroll
            for (int i = 0; i < 2; ++i)
                a[i] = *(const short8*)&sm.sA[cur][(16 * i + l15) * KP + kk * 32 + quad * 8];
#pragma unroll
            for (int i = 0; i < 2; ++i)
#pragma unroll
                for (int j = 0; j < 4; ++j)
                    acc[i][j] = MFMA(a[i], breg[j][kk], acc[i][j]);
        }

        if (t + nblocks < ntiles) {
            stage(cur ^ 1);
            if (t + 2 * nblocks < ntiles) issue(t + 2 * nblocks);
        }

#pragma unroll
        for (int i = 0; i < 2; ++i)
#pragma unroll
            for (int r = 0; r < 4; ++r) {
                float v0 = acc[i][0][r] + b1v[0];
                float v1 = acc[i][1][r] + b1v[1];
                float v2 = acc[i][2][r] + b1v[2];
                float v3 = acc[i][3][r] + b1v[3];
                acc[i][0][r] = v0; acc[i][1][r] = v1; acc[i][2][r] = v2; acc[i][3][r] = v3;
                float s  = (v0 + v1) + (v2 + v3);
                float ss = __builtin_fmaf(v0, v0, __builtin_fmaf(v1, v1,
                           __builtin_fmaf(v2, v2, v3 * v3)));
                s = rowsum16(s); ss = rowsum16(ss);
                if (l15 == 0) {
                    int row = 16 * i + quad * 4 + r;
                    *(float2*)&sm.rstat[row * 8 + cw * 2] = make_float2(s, ss);
                }
            }
        __syncthreads();

#pragma unroll
        for (int i = 0; i < 2; ++i)
#pragma unroll
            for (int r = 0; r < 4; ++r) {
                int row = 16 * i + quad * 4 + r;
                const float4* st = (const float4*)&sm.rstat[row * 8];
                float4 q0 = st[0], q1 = st[1];
                float s  = (q0.x + q0.z) + (q1.x + q1.z);
                float ss = (q0.y + q0.w) + (q1.y + q1.w);
                float mean = s * (1.f / 256.f);
                float var  = __builtin_fmaf(ss, 1.f / 256.f, -mean * mean);
                float rstd = __builtin_amdgcn_rsqf(var + 1e-5f);
                float nm = -mean * rstd;
                float spp = 0.f;
#pragma unroll
                for (int j = 0; j < 4; ++j) {
                    float tt = __builtin_fmaf(acc[i][j][r], rstd, nm);
                    float xn = __builtin_fmaf(tt, gv[j], bev[j]);
                    spp = __builtin_fmaf(gelu_fast(xn), w2v[j], spp);
                }
                spp = rowsum16(spp);
                if (l15 == 0) sm.spL[row * 4 + cw] = spp;
            }
        __syncthreads();

        if (tid < 32) {
            int e = t * 32 + tid;
            if (e < E) {
                const float4* sp = (const float4*)&sm.spL[tid * 4];
                float4 u0 = sp[0];
                out[e] = ((u0.x + u0.y) + (u0.z + u0.w)) + b2v;
            }
        }
        cur ^= 1;
    }
}

__global__ __launch_bounds__(256, 3)
void fused_all(const float* __restrict__ x, const int* __restrict__ ei,
               const float* __restrict__ sp_w1, const float* __restrict__ sp_b1,
               const float* __restrict__ sp_g, const float* __restrict__ sp_be,
               const float* __restrict__ sp_w2, const float* __restrict__ sp_b2,
               const float* __restrict__ fr_w1, const float* __restrict__ fr_b1,
               const float* __restrict__ fr_g, const float* __restrict__ fr_be,
               const float* __restrict__ fr_w2, const float* __restrict__ fr_b2,
               const float* __restrict__ ph_w1, const float* __restrict__ ph_b1,
               const float* __restrict__ ph_g, const float* __restrict__ ph_be,
               const float* __restrict__ ph_w2, const float* __restrict__ ph_b2,
               float* __restrict__ out_sp, float* __restrict__ out_rec,
               float* __restrict__ out_proj, int N, int E) {
    __shared__ SmemU sm;
    const int b = blockIdx.x;
    if (b < 128) {
        for (int tt = b; tt < (N + 63) / 64; tt += 128) {
            __syncthreads();
            mlp_tile<64, 128, 64, 4, false>(sm.a, x, fr_w1, fr_b1, fr_g, fr_be, fr_w2, fr_b2,
                                            out_rec, N, tt);
        }
    } else if (b < 256) {
        for (int tt = b - 128; tt < (N + 31) / 32; tt += 128) {
            __syncthreads();
            mlp_tile<64, 256, 128, 2, false>(sm.b, x, ph_w1, ph_b1, ph_g, ph_be, ph_w2, ph_b2,
                                             out_proj, N, tt);
        }
    } else {
        edge_role(sm.e, x, ei, sp_w1, sp_b1, sp_g, sp_be, sp_w2, sp_b2,
                  out_sp, E, b - 256, 1024);
    }
}
// ===========================================================================

extern "C" void kernel_launch(void* const* d_in, const int* in_sizes, int n_in,
                              void* d_out, int out_size, void* d_ws, size_t ws_size,
                              hipStream_t stream) {
    const float* x     = (const float*)d_in[0];
    const int*   ei    = (const int*)d_in[1];
    const float* sp_w1 = (const float*)d_in[2];
    const float* sp_b1 = (const float*)d_in[3];
    const float* sp_g  = (const float*)d_in[4];
    const float* sp_be = (const float*)d_in[5];
    const float* sp_w2 = (const float*)d_in[6];
    const float* sp_b2 = (const float*)d_in[7];
    const float* fr_w1 = (const float*)d_in[8];
    const float* fr_b1 = (const float*)d_in[9];
    const float* fr_g  = (const float*)d_in[10];
    const float* fr_be = (const float*)d_in[11];
    const float* fr_w2 = (const float*)d_in[12];
    const float* fr_b2 = (const float*)d_in[13];
    const float* ph_w1 = (const float*)d_in[14];
    const float* ph_b1 = (const float*)d_in[15];
    const float* ph_g  = (const float*)d_in[16];
    const float* ph_be = (const float*)d_in[17];
    const float* ph_w2 = (const float*)d_in[18];
    const float* ph_b2 = (const float*)d_in[19];

    const int N = in_sizes[0] / 64;
    const int E = in_sizes[1] / 2;

    float* out_sp   = (float*)d_out;
    float* out_rec  = out_sp + E;
    float* out_proj = out_rec + (size_t)N * 64;

    const size_t pbytes  = 2ull * (size_t)N * 256 * sizeof(unsigned short);
    const size_t wbytes  = 98304 * sizeof(unsigned short);   // packed weights
    const size_t needed  = pbytes;
    const size_t needed2 = pbytes + wbytes;

    const int ntN = (N + 63) / 64;             // proj tiles per plane
    const int nFR = (N + 63) / 64;             // FR tiles (64-row)
    const int nPH = (N + 31) / 32;             // PH tiles (32-row)

    if (ws_size >= needed2) {
        unsigned short* wp = (unsigned short*)d_ws;
        unsigned short* Pa = wp + 98304;
        unsigned short* Pb = Pa + (size_t)N * 256;
        const unsigned short* wp_sp  = wp;
        const unsigned short* wp_fr1 = wp + 32768;
        const unsigned short* wp_fr2 = wp + 40960;
        const unsigned short* wp_ph1 = wp + 49152;
        const unsigned short* wp_ph2 = wp + 65536;

        repack_kernel<<<dim3(384), dim3(256), 0, stream>>>(
            sp_w1, fr_w1, fr_w2, ph_w1, ph_w2, wp);

        prep_kernel<true><<<dim3(nPH + nFR + 2 * ntN), dim3(256), 0, stream>>>(
            x, wp_sp, sp_b1,
            wp_fr1, fr_b1, fr_g, fr_be, wp_fr2, fr_b2,
            wp_ph1, ph_b1, ph_g, ph_be, wp_ph2, ph_b2,
            Pa, Pb, out_rec, out_proj, N, ntN, nFR, nPH);

        edge_stream<<<dim3(4096), dim3(256), 0, stream>>>(
            Pa, Pb, ei, sp_g, sp_be, sp_w2, sp_b2, out_sp, E);
    } else if (ws_size >= needed) {
        unsigned short* Pa = (unsigned short*)d_ws;
        unsigned short* Pb = Pa + (size_t)N * 256;

        prep_kernel<false><<<dim3(nPH + nFR + 2 * ntN), dim3(256), 0, stream>>>(
            x, sp_w1, sp_b1,
            fr_w1, fr_b1, fr_g, fr_be, fr_w2, fr_b2,
            ph_w1, ph_b1, ph_g, ph_be, ph_w2, ph_b2,
            Pa, Pb, out_rec, out_proj, N, ntN, nFR, nPH);

        edge_stream<<<dim3(4096), dim3(256), 0, stream>>>(
            Pa, Pb, ei, sp_g, sp_be, sp_w2, sp_b2, out_sp, E);
    } else {
        fused_all<<<dim3(1280), dim3(256), 0, stream>>>(
            x, ei, sp_w1, sp_b1, sp_g, sp_be, sp_w2, sp_b2,
            fr_w1, fr_b1, fr_g, fr_be, fr_w2, fr_b2,
            ph_w1, ph_b1, ph_g, ph_be, ph_w2, ph_b2,
            out_sp, out_rec, out_proj, N, E);
    }
}